// Round 1
// baseline (312.081 us; speedup 1.0000x reference)
//
#include <hip/hip_runtime.h>
#include <hip/hip_bf16.h>

#define H_ 128
#define W_ 128
#define B_ 8
#define CIN_ 64
#define COUT_ 64

typedef __attribute__((ext_vector_type(8))) short bf16x8;
typedef __attribute__((ext_vector_type(4))) float f32x4;

static __device__ __forceinline__ unsigned short f2bf(float f) {
  union { float f; unsigned int u; } a; a.f = f;
  unsigned int u = a.u;
  return (unsigned short)((u + 0x7fffu + ((u >> 16) & 1u)) >> 16);  // RNE, finite inputs
}
static __device__ __forceinline__ float bf2f(unsigned short h) {
  union { unsigned int u; float f; } a; a.u = ((unsigned int)h) << 16; return a.f;
}

// ---------------- transpose deform_w (o,c,k) f32 -> (k,o,c) bf16 ----------------
__global__ __launch_bounds__(256) void transpose_w(const float* __restrict__ dw,
                                                   unsigned short* __restrict__ dwt) {
  int id = blockIdx.x * 256 + threadIdx.x;   // id = k*4096 + o*64 + c
  int c = id & 63;
  int o = (id >> 6) & 63;
  int k = id >> 12;
  dwt[id] = f2bf(dw[(o * 64 + c) * 9 + k]);
}

// ---------------- Kernel A: offset conv 64->18, 3x3, SAME, fp32 ----------------
// grid = B * 8 * 8 (16x16 pixel tiles), block 256
__global__ __launch_bounds__(256) void offs_conv(const float* __restrict__ x,
    const float* __restrict__ w, const float* __restrict__ bias,
    float* __restrict__ off) {
  __shared__ float xt[8][18][20];
  const int tile = blockIdx.x;
  const int b = tile >> 6;
  const int ty = ((tile >> 3) & 7) << 4;
  const int tx = (tile & 7) << 4;
  const int lx = threadIdx.x & 15;
  const int lyr = threadIdx.x >> 4;
  float acc[18];
#pragma unroll
  for (int o = 0; o < 18; ++o) acc[o] = 0.f;

  for (int cc = 0; cc < CIN_; cc += 8) {
    __syncthreads();
    for (int idx = threadIdx.x; idx < 8 * 18 * 18; idx += 256) {
      int c = idx / 324;
      int r = idx - c * 324;
      int yy = r / 18;
      int xx = r - yy * 18;
      int gy = ty + yy - 1, gx = tx + xx - 1;
      float v = 0.f;
      if ((unsigned)gy < (unsigned)H_ && (unsigned)gx < (unsigned)W_)
        v = x[((b * CIN_ + cc + c) * H_ + gy) * W_ + gx];
      xt[c][yy][xx] = v;
    }
    __syncthreads();
#pragma unroll
    for (int c = 0; c < 8; ++c) {
      float xv[9];
#pragma unroll
      for (int t = 0; t < 9; ++t) xv[t] = xt[c][lyr + t / 3][lx + t % 3];
      const float* wp = w + (cc + c) * 9;   // + o*(64*9) + t
#pragma unroll
      for (int o = 0; o < 18; ++o) {
        const float* wo = wp + o * (CIN_ * 9);   // uniform address -> s_load
        float s = acc[o];
#pragma unroll
        for (int t = 0; t < 9; ++t) s = fmaf(xv[t], wo[t], s);
        acc[o] = s;
      }
    }
  }
  const int gy = ty + lyr, gx = tx + lx;
#pragma unroll
  for (int o = 0; o < 18; ++o)
    off[((b * 18 + o) * H_ + gy) * W_ + gx] = acc[o] + bias[o];
}

// ---------------- Kernel B: deformable sample + GEMM (MFMA bf16) ----------------
// grid = B * 16 * 16 (8x8 pixel tiles), block 256 (4 waves; wave w owns couts 16w..16w+15)
// x-tile: rows [ty-3, ty+11] (15), cols [tx-4, tx+11] (16), layout [pt][c] bf16,
// 16B-granular XOR swizzle (c8 ^ (pt&7)).

__device__ __forceinline__ void corner8(const float* __restrict__ x,
    const unsigned short* __restrict__ ldsx, int b, int iy, int ix,
    int oy, int ox, int c8, float g[8]) {
  int ly = iy - oy, lx = ix - ox;
  if ((unsigned)ly < 15u && (unsigned)lx < 16u) {
    int pt = (ly << 4) | lx;
    bf16x8 q = *(const bf16x8*)&ldsx[(pt << 6) | ((c8 ^ (pt & 7)) << 3)];
#pragma unroll
    for (int ci = 0; ci < 8; ++ci) g[ci] = bf2f((unsigned short)q[ci]);
  } else if ((unsigned)iy < (unsigned)H_ && (unsigned)ix < (unsigned)W_) {
#pragma unroll
    for (int ci = 0; ci < 8; ++ci)
      g[ci] = x[((b * CIN_ + (c8 << 3) + ci) * H_ + iy) * W_ + ix];
  } else {
#pragma unroll
    for (int ci = 0; ci < 8; ++ci) g[ci] = 0.f;
  }
}

__global__ __launch_bounds__(256) void deform_main(const float* __restrict__ x,
    const float* __restrict__ off, const unsigned short* __restrict__ dwt,
    const float* __restrict__ db, float* __restrict__ out) {
  __shared__ unsigned short ldsx[240 * 64];   // 30.0 KB
  __shared__ unsigned short ldsS[64 * 64];    // 8 KB  (one tap: S[pix][c])
  __shared__ int   p_iy[576], p_ix[576];
  __shared__ float p_wy[576], p_wx[576];

  const int tid = threadIdx.x;
  const int blk = blockIdx.x;
  const int b = blk >> 8;
  const int ty = ((blk >> 4) & 15) << 3;
  const int tx = (blk & 15) << 3;
  const int oy = ty - 3, ox = tx - 4;
  const int lane = tid & 63;
  const int wv = tid >> 6;
  const int o_m = (wv << 4) + (lane & 15);   // A-frag row (cout)
  const int kgrp = lane >> 4;                // 0..3

  // ---- phase 0a: sample-point table (576 = 64 pix x 9 taps) ----
  for (int u = tid; u < 576; u += 256) {
    int pix = u & 63, k = u >> 6;
    int yy = ty + (pix >> 3), xx = tx + (pix & 7);
    float dy = off[((b * 18 + 2 * k) * H_ + yy) * W_ + xx];
    float dx = off[((b * 18 + 2 * k + 1) * H_ + yy) * W_ + xx];
    float py = (float)(yy + k / 3 - 1) + dy;
    float px = (float)(xx + k % 3 - 1) + dx;
    float fy = floorf(py), fx = floorf(px);
    p_iy[u] = (int)fy; p_ix[u] = (int)fx;
    p_wy[u] = py - fy; p_wx[u] = px - fx;
  }

  // ---- phase 0b: stage x tile (15 rows x 16 cols x 64 ch) as swizzled bf16 ----
  for (int i = 0; i < 15; ++i) {
    int it = tid + (i << 8);          // 3840 = 64c * 15rows * 4 quads
    int c = it / 60;
    int r = it - c * 60;
    int lyy = r >> 2;
    int xq = r & 3;
    int gy = oy + lyy;
    int gx0 = ox + (xq << 2);         // multiple of 4 -> float4 fully in or out
    float4 v = make_float4(0.f, 0.f, 0.f, 0.f);
    if ((unsigned)gy < (unsigned)H_ && (unsigned)gx0 < (unsigned)W_)
      v = *(const float4*)&x[((b * CIN_ + c) * H_ + gy) * W_ + gx0];
    int c8 = c >> 3, c0 = c & 7;
    const float vv[4] = {v.x, v.y, v.z, v.w};
#pragma unroll
    for (int q = 0; q < 4; ++q) {
      int pt = (lyy << 4) | ((xq << 2) + q);
      ldsx[(pt << 6) | ((c8 ^ (pt & 7)) << 3) | c0] = f2bf(vv[q]);
    }
  }
  __syncthreads();

  f32x4 acc[4];
#pragma unroll
  for (int nt = 0; nt < 4; ++nt) acc[nt] = (f32x4){0.f, 0.f, 0.f, 0.f};

#pragma unroll
  for (int k = 0; k < 9; ++k) {
    // A-fragments for this tap (latency hidden under the build phase)
    bf16x8 af0 = *(const bf16x8*)&dwt[(k << 12) + (o_m << 6) + (kgrp << 3)];
    bf16x8 af1 = *(const bf16x8*)&dwt[(k << 12) + (o_m << 6) + 32 + (kgrp << 3)];

    // ---- build S chunk: 64 pix x 64 ch for tap k ----
#pragma unroll
    for (int i = 0; i < 2; ++i) {
      int u = tid + (i << 8);
      int pix = u >> 3, c8 = u & 7;
      int pd = (k << 6) | pix;
      int iy = p_iy[pd], ix = p_ix[pd];
      float wy = p_wy[pd], wx = p_wx[pd];
      float w00 = (1.f - wy) * (1.f - wx), w01 = (1.f - wy) * wx;
      float w10 = wy * (1.f - wx),         w11 = wy * wx;
      float g00[8], g01[8], g10[8], g11[8];
      corner8(x, ldsx, b, iy,     ix,     oy, ox, c8, g00);
      corner8(x, ldsx, b, iy,     ix + 1, oy, ox, c8, g01);
      corner8(x, ldsx, b, iy + 1, ix,     oy, ox, c8, g10);
      corner8(x, ldsx, b, iy + 1, ix + 1, oy, ox, c8, g11);
      bf16x8 sv;
#pragma unroll
      for (int ci = 0; ci < 8; ++ci) {
        float v = g00[ci] * w00 + g01[ci] * w01 + g10[ci] * w10 + g11[ci] * w11;
        sv[ci] = (short)f2bf(v);
      }
      *(bf16x8*)&ldsS[(pix << 6) | ((c8 ^ (pix & 7)) << 3)] = sv;
    }
    __syncthreads();

    // ---- MFMA: 2 K-halves x 4 N-tiles ----
#pragma unroll
    for (int hf = 0; hf < 2; ++hf) {
#pragma unroll
      for (int nt = 0; nt < 4; ++nt) {
        int pix = (nt << 4) | (lane & 15);
        int c8 = (hf << 2) | kgrp;
        bf16x8 bf = *(const bf16x8*)&ldsS[(pix << 6) | ((c8 ^ (pix & 7)) << 3)];
        acc[nt] = __builtin_amdgcn_mfma_f32_16x16x32_bf16(hf ? af1 : af0, bf, acc[nt], 0, 0, 0);
      }
    }
    __syncthreads();
  }

  // ---- epilogue: D layout col=lane&15 (pix), row=(lane>>4)*4+j (cout_local) ----
#pragma unroll
  for (int nt = 0; nt < 4; ++nt) {
    int pix = (nt << 4) | (lane & 15);
    int gy = ty + (pix >> 3), gx = tx + (pix & 7);
#pragma unroll
    for (int j = 0; j < 4; ++j) {
      int o = (wv << 4) + (kgrp << 2) + j;
      float v = acc[nt][j] + db[o];
      out[((b * COUT_ + o) * H_ + gy) * W_ + gx] = v > 0.f ? v : 0.f;
    }
  }
}

extern "C" void kernel_launch(void* const* d_in, const int* in_sizes, int n_in,
                              void* d_out, int out_size, void* d_ws, size_t ws_size,
                              hipStream_t stream) {
  const float* x  = (const float*)d_in[0];
  const float* ow = (const float*)d_in[1];
  const float* ob = (const float*)d_in[2];
  const float* dw = (const float*)d_in[3];
  const float* db = (const float*)d_in[4];
  float* out = (float*)d_out;

  float* off = (float*)d_ws;                                   // 8*18*128*128 f32 = 9.44 MB
  unsigned short* dwt = (unsigned short*)((char*)d_ws + 9437184);  // 9*64*64 bf16

  hipLaunchKernelGGL(transpose_w, dim3(144), dim3(256), 0, stream, dw, dwt);
  hipLaunchKernelGGL(offs_conv, dim3(512), dim3(256), 0, stream, x, ow, ob, off);
  hipLaunchKernelGGL(deform_main, dim3(2048), dim3(256), 0, stream, x, off, dwt, db, out);
}

// Round 2
// 190.334 us; speedup vs baseline: 1.6396x; 1.6396x over previous
//
#include <hip/hip_runtime.h>
#include <hip/hip_bf16.h>

#define H_ 128
#define W_ 128
#define B_ 8
#define CIN_ 64
#define COUT_ 64

typedef __attribute__((ext_vector_type(8))) short bf16x8;
typedef __attribute__((ext_vector_type(4))) float f32x4;

static __device__ __forceinline__ unsigned short f2bf(float f) {
  union { float f; unsigned int u; } a; a.f = f;
  unsigned int u = a.u;
  return (unsigned short)((u + 0x7fffu + ((u >> 16) & 1u)) >> 16);  // RNE, finite inputs
}
static __device__ __forceinline__ float bf2f(unsigned short h) {
  union { unsigned int u; float f; } a; a.u = ((unsigned int)h) << 16; return a.f;
}

// ---------------- prep: transpose both weight tensors to bf16 ----------------
// dwt: (o,c,k) f32 -> [k][o(64)][c(64)] bf16      (36864 elems)
// owt: (18,c,t) f32 -> [t][om(32, zero-pad)][c(64)] bf16  (18432 elems)
__global__ __launch_bounds__(256) void prep_w(const float* __restrict__ dw,
    const float* __restrict__ ow, unsigned short* __restrict__ dwt,
    unsigned short* __restrict__ owt) {
  int id = blockIdx.x * 256 + threadIdx.x;
  if (id < 36864) {
    int c = id & 63, o = (id >> 6) & 63, k = id >> 12;
    dwt[id] = f2bf(dw[(o * 64 + c) * 9 + k]);
  } else if (id < 36864 + 18432) {
    int j = id - 36864;
    int c = j & 63, om = (j >> 6) & 31, t = j >> 11;
    owt[j] = f2bf(om < 18 ? ow[(om * 64 + c) * 9 + t] : 0.f);
  }
}

// ---------------- fused deformable block ----------------
// grid = B * 16 * 16 (8x8 pixel tiles), block 256 (4 waves)
// x-tile: rows [ty-3, ty+11] (15), cols [tx-4, tx+11] (16), layout [pt][c] bf16,
// 16B-granular XOR swizzle (c8 ^ (pt&7)).
// Phase 1: offset conv via MFMA from the staged tile (each wave: its 16 pixels).
// Phase 2: sample-point tables. Phase 3: per-tap sample->ldsS->MFMA main GEMM.

__device__ __forceinline__ void corner8(const float* __restrict__ x,
    const unsigned short* __restrict__ ldsx, int b, int iy, int ix,
    int oy, int ox, int c8, float g[8]) {
  int ly = iy - oy, lx = ix - ox;
  if ((unsigned)ly < 15u && (unsigned)lx < 16u) {
    int pt = (ly << 4) | lx;
    bf16x8 q = *(const bf16x8*)&ldsx[(pt << 6) | ((c8 ^ (pt & 7)) << 3)];
#pragma unroll
    for (int ci = 0; ci < 8; ++ci) g[ci] = bf2f((unsigned short)q[ci]);
  } else if ((unsigned)iy < (unsigned)H_ && (unsigned)ix < (unsigned)W_) {
#pragma unroll
    for (int ci = 0; ci < 8; ++ci)
      g[ci] = x[((b * CIN_ + (c8 << 3) + ci) * H_ + iy) * W_ + ix];
  } else {
#pragma unroll
    for (int ci = 0; ci < 8; ++ci) g[ci] = 0.f;
  }
}

__global__ __launch_bounds__(256) void deform_main(const float* __restrict__ x,
    const unsigned short* __restrict__ owt, const float* __restrict__ ob,
    const unsigned short* __restrict__ dwt, const float* __restrict__ db,
    float* __restrict__ out) {
  __shared__ unsigned short ldsx[240 * 64];   // 30 KB
  __shared__ unsigned short ldsS[64 * 64];    // 8 KB  (one tap: S[pix][c])
  __shared__ float offs_lds[64][18];          // 4.5 KB
  __shared__ int   p_iy[576], p_ix[576];
  __shared__ float p_wy[576], p_wx[576];

  const int tid = threadIdx.x;
  const int blk = blockIdx.x;
  const int b = blk >> 8;
  const int ty = ((blk >> 4) & 15) << 3;
  const int tx = (blk & 15) << 3;
  const int oy = ty - 3, ox = tx - 4;
  const int lane = tid & 63;
  const int wv = tid >> 6;
  const int o_m = (wv << 4) + (lane & 15);   // main-GEMM A-frag row (cout)
  const int kgrp = lane >> 4;                // 0..3

  // ---- phase 0: stage x tile (15 rows x 16 cols x 64 ch) as swizzled bf16 ----
  for (int i = 0; i < 15; ++i) {
    int it = tid + (i << 8);          // 3840 units = 64c * 15rows * 4 quads
    int c = it / 60;
    int r = it - c * 60;
    int lyy = r >> 2;
    int xq = r & 3;
    int gy = oy + lyy;
    int gx0 = ox + (xq << 2);         // multiple of 4 -> float4 fully in or out
    float4 v = make_float4(0.f, 0.f, 0.f, 0.f);
    if ((unsigned)gy < (unsigned)H_ && (unsigned)gx0 < (unsigned)W_)
      v = *(const float4*)&x[((b * CIN_ + c) * H_ + gy) * W_ + gx0];
    int c8 = c >> 3, c0 = c & 7;
    const float vv[4] = {v.x, v.y, v.z, v.w};
#pragma unroll
    for (int q = 0; q < 4; ++q) {
      int pt = (lyy << 4) | ((xq << 2) + q);
      ldsx[(pt << 6) | ((c8 ^ (pt & 7)) << 3) | c0] = f2bf(vv[q]);
    }
  }
  __syncthreads();

  // ---- phase 1: offset conv via MFMA. wave wv handles pixels [wv*16, wv*16+16) ----
  {
    f32x4 aoff0 = (f32x4){0.f, 0.f, 0.f, 0.f};
    f32x4 aoff1 = (f32x4){0.f, 0.f, 0.f, 0.f};
    const int pixw = (wv << 4) | (lane & 15);
#pragma unroll
    for (int t = 0; t < 9; ++t) {
      const int ti = t / 3 - 1, tj = t % 3 - 1;
      const int ly = (pixw >> 3) + ti + 3;    // in [2,12]
      const int lx = (pixw & 7) + tj + 4;     // in [3,12]
      const int pt = (ly << 4) | lx;
#pragma unroll
      for (int hf = 0; hf < 2; ++hf) {
        const int c8 = (hf << 2) | kgrp;
        bf16x8 bfr = *(const bf16x8*)&ldsx[(pt << 6) | ((c8 ^ (pt & 7)) << 3)];
        bf16x8 a0 = *(const bf16x8*)&owt[(((t << 5) | (lane & 15)) << 6) | (c8 << 3)];
        bf16x8 a1 = *(const bf16x8*)&owt[(((t << 5) | 16 | (lane & 15)) << 6) | (c8 << 3)];
        aoff0 = __builtin_amdgcn_mfma_f32_16x16x32_bf16(a0, bfr, aoff0, 0, 0, 0);
        aoff1 = __builtin_amdgcn_mfma_f32_16x16x32_bf16(a1, bfr, aoff1, 0, 0, 0);
      }
    }
    // scatter offsets (+bias) to LDS: D layout col=lane&15 (pix), row=(lane>>4)*4+j (o)
#pragma unroll
    for (int j = 0; j < 4; ++j) {
      int o = (kgrp << 2) + j;
      offs_lds[pixw][o] = aoff0[j] + ob[o];
      int o1 = 16 + o;
      if (o1 < 18) offs_lds[pixw][o1] = aoff1[j] + ob[o1];
    }
  }
  __syncthreads();

  // ---- phase 2: sample-point table (576 = 64 pix x 9 taps) ----
  for (int u = tid; u < 576; u += 256) {
    int pix = u & 63, k = u >> 6;
    int yy = ty + (pix >> 3), xx = tx + (pix & 7);
    float dy = offs_lds[pix][2 * k];
    float dx = offs_lds[pix][2 * k + 1];
    float py = (float)(yy + k / 3 - 1) + dy;
    float px = (float)(xx + k % 3 - 1) + dx;
    float fy = floorf(py), fx = floorf(px);
    p_iy[u] = (int)fy; p_ix[u] = (int)fx;
    p_wy[u] = py - fy; p_wx[u] = px - fx;
  }
  __syncthreads();

  f32x4 acc[4];
#pragma unroll
  for (int nt = 0; nt < 4; ++nt) acc[nt] = (f32x4){0.f, 0.f, 0.f, 0.f};

#pragma unroll
  for (int k = 0; k < 9; ++k) {
    // A-fragments for this tap (latency hidden under the build phase)
    bf16x8 af0 = *(const bf16x8*)&dwt[(k << 12) + (o_m << 6) + (kgrp << 3)];
    bf16x8 af1 = *(const bf16x8*)&dwt[(k << 12) + (o_m << 6) + 32 + (kgrp << 3)];

    // ---- build S chunk: 64 pix x 64 ch for tap k ----
#pragma unroll
    for (int i = 0; i < 2; ++i) {
      int u = tid + (i << 8);
      int pix = u >> 3, c8 = u & 7;
      int pd = (k << 6) | pix;
      int iy = p_iy[pd], ix = p_ix[pd];
      float wy = p_wy[pd], wx = p_wx[pd];
      float w00 = (1.f - wy) * (1.f - wx), w01 = (1.f - wy) * wx;
      float w10 = wy * (1.f - wx),         w11 = wy * wx;
      float g00[8], g01[8], g10[8], g11[8];
      corner8(x, ldsx, b, iy,     ix,     oy, ox, c8, g00);
      corner8(x, ldsx, b, iy,     ix + 1, oy, ox, c8, g01);
      corner8(x, ldsx, b, iy + 1, ix,     oy, ox, c8, g10);
      corner8(x, ldsx, b, iy + 1, ix + 1, oy, ox, c8, g11);
      bf16x8 sv;
#pragma unroll
      for (int ci = 0; ci < 8; ++ci) {
        float v = g00[ci] * w00 + g01[ci] * w01 + g10[ci] * w10 + g11[ci] * w11;
        sv[ci] = (short)f2bf(v);
      }
      *(bf16x8*)&ldsS[(pix << 6) | ((c8 ^ (pix & 7)) << 3)] = sv;
    }
    __syncthreads();

    // ---- MFMA: 2 K-halves x 4 N-tiles ----
#pragma unroll
    for (int hf = 0; hf < 2; ++hf) {
#pragma unroll
      for (int nt = 0; nt < 4; ++nt) {
        int pix = (nt << 4) | (lane & 15);
        int c8 = (hf << 2) | kgrp;
        bf16x8 bf = *(const bf16x8*)&ldsS[(pix << 6) | ((c8 ^ (pix & 7)) << 3)];
        acc[nt] = __builtin_amdgcn_mfma_f32_16x16x32_bf16(hf ? af1 : af0, bf, acc[nt], 0, 0, 0);
      }
    }
    __syncthreads();
  }

  // ---- epilogue: D layout col=lane&15 (pix), row=(lane>>4)*4+j (cout_local) ----
#pragma unroll
  for (int nt = 0; nt < 4; ++nt) {
    int pix = (nt << 4) | (lane & 15);
    int gy = ty + (pix >> 3), gx = tx + (pix & 7);
#pragma unroll
    for (int j = 0; j < 4; ++j) {
      int o = (wv << 4) + (kgrp << 2) + j;
      float v = acc[nt][j] + db[o];
      out[((b * COUT_ + o) * H_ + gy) * W_ + gx] = v > 0.f ? v : 0.f;
    }
  }
}

extern "C" void kernel_launch(void* const* d_in, const int* in_sizes, int n_in,
                              void* d_out, int out_size, void* d_ws, size_t ws_size,
                              hipStream_t stream) {
  const float* x  = (const float*)d_in[0];
  const float* ow = (const float*)d_in[1];
  const float* ob = (const float*)d_in[2];
  const float* dw = (const float*)d_in[3];
  const float* db = (const float*)d_in[4];
  float* out = (float*)d_out;

  unsigned short* dwt = (unsigned short*)d_ws;                    // 36864 bf16
  unsigned short* owt = (unsigned short*)((char*)d_ws + 73728);   // 18432 bf16

  hipLaunchKernelGGL(prep_w, dim3(216), dim3(256), 0, stream, dw, ow, dwt, owt);
  hipLaunchKernelGGL(deform_main, dim3(2048), dim3(256), 0, stream,
                     x, owt, ob, dwt, db, out);
}